// Round 1
// baseline (420.439 us; speedup 1.0000x reference)
//
#include <hip/hip_runtime.h>
#include <math.h>

#define BB 4
#define C 64
#define H 128
#define W 128
#define K 9
#define HW (H*W)

// ---------------- prep: transpose weights for uniform/contiguous scalar loads
// wt  [9][64][64]  <- w_dcn [64][64][3][3]   (o,c,k) -> [k][c][o]
// wot [64][9][27]  <- w_off [27][64][3][3]   (o,c,t) -> [c][t][o]
__global__ __launch_bounds__(256) void prep_kernel(
    const float* __restrict__ wd, const float* __restrict__ woff,
    float* __restrict__ wt, float* __restrict__ wot) {
  int i = blockIdx.x * 256 + threadIdx.x;
  if (i < C * C * K) {          // 36864
    int k = i % K;
    int c = (i / K) % C;
    int o = i / (K * C);
    wt[(k * C + c) * C + o] = wd[i];
  }
  if (i < 27 * C * K) {         // 15552
    int t = i % K;
    int c = (i / K) % C;
    int o = i / (K * C);
    wot[(c * K + t) * 27 + o] = woff[i];
  }
}

// ---------------- conv_offset: off_out[b][27][h][w] = conv3x3(c_in) + b_off
__global__ __launch_bounds__(256) void conv_off_kernel(
    const float* __restrict__ cin, const float* __restrict__ wot,
    const float* __restrict__ boff, float* __restrict__ off_out) {
  int tid = blockIdx.x * 256 + threadIdx.x;   // over B*H*W
  int w = tid & (W - 1);
  int h = (tid >> 7) & (H - 1);
  int b = tid >> 14;
  const float* cb = cin + (size_t)b * C * HW;

  float acc[27];
#pragma unroll
  for (int o = 0; o < 27; ++o) acc[o] = boff[o];

#pragma unroll 2
  for (int c = 0; c < C; ++c) {
    const float* cc = cb + c * HW;
    float v[9];
#pragma unroll
    for (int t = 0; t < 9; ++t) {
      int yy = h + t / 3 - 1;
      int xx = w + t % 3 - 1;
      bool ok = (yy >= 0) && (yy < H) && (xx >= 0) && (xx < W);
      v[t] = ok ? cc[yy * W + xx] : 0.0f;
    }
    const float* wc = wot + c * (9 * 27);   // uniform address -> s_loads
#pragma unroll
    for (int t = 0; t < 9; ++t)
#pragma unroll
      for (int o = 0; o < 27; ++o)
        acc[o] = fmaf(wc[t * 27 + o], v[t], acc[o]);
  }

  int p = h * W + w;
#pragma unroll
  for (int o = 0; o < 27; ++o)
    off_out[((size_t)b * 27 + o) * HW + p] = acc[o];
}

// ---------------- main: modulated deformable conv
__global__ __launch_bounds__(256) void dcn_main_kernel(
    const float* __restrict__ x, const float* __restrict__ off,
    const float* __restrict__ wt, const float* __restrict__ bd,
    float* __restrict__ out) {
  int tid = blockIdx.x * 256 + threadIdx.x;   // over B*H*W
  int w = tid & (W - 1);
  int h = (tid >> 7) & (H - 1);
  int b = tid >> 14;
  int p = h * W + w;

  const float* xb = x + (size_t)b * C * HW;
  const float* ob = off + (size_t)b * 27 * HW;

  float acc[C];
#pragma unroll
  for (int o = 0; o < C; ++o) acc[o] = 0.0f;

#pragma unroll 1
  for (int k = 0; k < K; ++k) {
    float dy = ob[(2 * k) * HW + p];
    float dx = ob[(2 * k + 1) * HW + p];
    float mv = ob[(18 + k) * HW + p];
    float m = 1.0f / (1.0f + __expf(-mv));

    float py = (float)h + (float)(k / 3 - 1) + dy;
    float px = (float)w + (float)(k % 3 - 1) + dx;
    float y0f = floorf(py), x0f = floorf(px);
    int y0 = (int)y0f, x0 = (int)x0f;
    float wy1 = py - y0f, wx1 = px - x0f;
    float wy0 = 1.0f - wy1, wx0 = 1.0f - wx1;

    bool y0v = (y0 >= 0) && (y0 < H);
    bool y1v = (y0 + 1 >= 0) && (y0 + 1 < H);
    bool x0v = (x0 >= 0) && (x0 < W);
    bool x1v = (x0 + 1 >= 0) && (x0 + 1 < W);
    int y0c = min(max(y0, 0), H - 1), y1c = min(max(y0 + 1, 0), H - 1);
    int x0c = min(max(x0, 0), W - 1), x1c = min(max(x0 + 1, 0), W - 1);

    // fold mask into corner weights (saves a mul per c)
    float w00 = wy0 * wx0 * (float)(y0v && x0v) * m;
    float w01 = wy0 * wx1 * (float)(y0v && x1v) * m;
    float w10 = wy1 * wx0 * (float)(y1v && x0v) * m;
    float w11 = wy1 * wx1 * (float)(y1v && x1v) * m;

    int i00 = y0c * W + x0c, i01 = y0c * W + x1c;
    int i10 = y1c * W + x0c, i11 = y1c * W + x1c;

    const float* wk = wt + k * (C * C);       // [c][o], uniform -> s_loads

#pragma unroll 2
    for (int c = 0; c < C; ++c) {
      const float* xc = xb + c * HW;
      float s = w00 * xc[i00] + w01 * xc[i01] + w10 * xc[i10] + w11 * xc[i11];
      const float* wc = wk + c * C;           // 64 contiguous floats, uniform
#pragma unroll
      for (int o = 0; o < C; ++o)
        acc[o] = fmaf(wc[o], s, acc[o]);
    }
  }

#pragma unroll
  for (int o = 0; o < C; ++o)
    out[((size_t)(b * C + o)) * HW + p] = acc[o] + bd[o];
}

extern "C" void kernel_launch(void* const* d_in, const int* in_sizes, int n_in,
                              void* d_out, int out_size, void* d_ws, size_t ws_size,
                              hipStream_t stream) {
  const float* x    = (const float*)d_in[0];
  const float* c    = (const float*)d_in[1];
  const float* woff = (const float*)d_in[2];
  const float* boff = (const float*)d_in[3];
  const float* wdcn = (const float*)d_in[4];
  const float* bdcn = (const float*)d_in[5];
  float* out = (float*)d_out;

  float* wsf = (float*)d_ws;
  float* off_out = wsf;                       // 4*27*128*128 = 1,769,472 floats
  float* wt  = wsf + (size_t)BB * 27 * HW;    // 36,864 floats
  float* wot = wt + C * C * K;                // 15,552 floats

  prep_kernel<<<(C * C * K + 255) / 256, 256, 0, stream>>>(wdcn, woff, wt, wot);

  int npix = BB * H * W;                      // 65536
  conv_off_kernel<<<npix / 256, 256, 0, stream>>>(c, wot, boff, off_out);
  dcn_main_kernel<<<npix / 256, 256, 0, stream>>>(x, off_out, wt, bdcn, out);
}

// Round 2
// 397.139 us; speedup vs baseline: 1.0587x; 1.0587x over previous
//
#include <hip/hip_runtime.h>
#include <math.h>

#define BB 4
#define C 64
#define H 128
#define W 128
#define K 9
#define HW (H*W)

// ---------------- prep: transpose weights for uniform/contiguous scalar loads
// wt  [9][64][64]  <- w_dcn [64][64][3][3]   (o,c,k) -> [k][c][o]
// wot [64][9][27]  <- w_off [27][64][3][3]   (o,c,t) -> [c][t][o]
__global__ __launch_bounds__(256) void prep_kernel(
    const float* __restrict__ wd, const float* __restrict__ woff,
    float* __restrict__ wt, float* __restrict__ wot) {
  int i = blockIdx.x * 256 + threadIdx.x;
  if (i < C * C * K) {          // 36864
    int k = i % K;
    int c = (i / K) % C;
    int o = i / (K * C);
    wt[(k * C + c) * C + o] = wd[i];
  }
  if (i < 27 * C * K) {         // 15552
    int t = i % K;
    int c = (i / K) % C;
    int o = i / (K * C);
    wot[(c * K + t) * 27 + o] = woff[i];
  }
}

// ---------------- conv_offset: off_out[b][27][h][w] = conv3x3(c_in) + b_off
// grid: (npix/256, 3)  — blockIdx.y picks a 9-wide output-channel chunk
__global__ __launch_bounds__(256) void conv_off_kernel(
    const float* __restrict__ cin, const float* __restrict__ wot,
    const float* __restrict__ boff, float* __restrict__ off_out) {
  int tid = blockIdx.x * 256 + threadIdx.x;   // over B*H*W
  int o0 = blockIdx.y * 9;
  int w = tid & (W - 1);
  int h = (tid >> 7) & (H - 1);
  int b = tid >> 14;
  const float* cb = cin + (size_t)b * C * HW;

  float acc[9];
#pragma unroll
  for (int o = 0; o < 9; ++o) acc[o] = boff[o0 + o];

#pragma unroll 2
  for (int c = 0; c < C; ++c) {
    const float* cc = cb + c * HW;
    float v[9];
#pragma unroll
    for (int t = 0; t < 9; ++t) {
      int yy = h + t / 3 - 1;
      int xx = w + t % 3 - 1;
      bool ok = (yy >= 0) && (yy < H) && (xx >= 0) && (xx < W);
      v[t] = ok ? cc[yy * W + xx] : 0.0f;
    }
    const float* wc = wot + c * (9 * 27) + o0;  // uniform address -> s_loads
#pragma unroll
    for (int t = 0; t < 9; ++t)
#pragma unroll
      for (int o = 0; o < 9; ++o)
        acc[o] = fmaf(wc[t * 27 + o], v[t], acc[o]);
  }

  int p = h * W + w;
#pragma unroll
  for (int o = 0; o < 9; ++o)
    off_out[((size_t)b * 27 + o0 + o) * HW + p] = acc[o];
}

// ---------------- main: modulated deformable conv
// grid: (npix/256, 4) — blockIdx.y picks a 16-wide output-channel chunk
__global__ __launch_bounds__(256) void dcn_main_kernel(
    const float* __restrict__ x, const float* __restrict__ off,
    const float* __restrict__ wt, const float* __restrict__ bd,
    float* __restrict__ out) {
  int tid = blockIdx.x * 256 + threadIdx.x;   // over B*H*W
  int o0 = blockIdx.y * 16;
  int w = tid & (W - 1);
  int h = (tid >> 7) & (H - 1);
  int b = tid >> 14;
  int p = h * W + w;

  const float* xb = x + (size_t)b * C * HW;
  const float* ob = off + (size_t)b * 27 * HW;

  float acc[16];
#pragma unroll
  for (int o = 0; o < 16; ++o) acc[o] = 0.0f;

#pragma unroll 1
  for (int k = 0; k < K; ++k) {
    float dy = ob[(2 * k) * HW + p];
    float dx = ob[(2 * k + 1) * HW + p];
    float mv = ob[(18 + k) * HW + p];
    float m = 1.0f / (1.0f + __expf(-mv));

    float py = (float)h + (float)(k / 3 - 1) + dy;
    float px = (float)w + (float)(k % 3 - 1) + dx;
    float y0f = floorf(py), x0f = floorf(px);
    int y0 = (int)y0f, x0 = (int)x0f;
    float wy1 = py - y0f, wx1 = px - x0f;
    float wy0 = 1.0f - wy1, wx0 = 1.0f - wx1;

    bool y0v = (y0 >= 0) && (y0 < H);
    bool y1v = (y0 + 1 >= 0) && (y0 + 1 < H);
    bool x0v = (x0 >= 0) && (x0 < W);
    bool x1v = (x0 + 1 >= 0) && (x0 + 1 < W);
    int y0c = min(max(y0, 0), H - 1), y1c = min(max(y0 + 1, 0), H - 1);
    int x0c = min(max(x0, 0), W - 1), x1c = min(max(x0 + 1, 0), W - 1);

    // fold mask into corner weights (saves a mul per c)
    float w00 = wy0 * wx0 * (float)(y0v && x0v) * m;
    float w01 = wy0 * wx1 * (float)(y0v && x1v) * m;
    float w10 = wy1 * wx0 * (float)(y1v && x0v) * m;
    float w11 = wy1 * wx1 * (float)(y1v && x1v) * m;

    int i00 = y0c * W + x0c, i01 = y0c * W + x1c;
    int i10 = y1c * W + x0c, i11 = y1c * W + x1c;

    const float* wk = wt + k * (C * C) + o0;  // [c][o-chunk], uniform -> s_loads

#pragma unroll 2
    for (int c = 0; c < C; ++c) {
      const float* xc = xb + c * HW;
      float s = w00 * xc[i00] + w01 * xc[i01] + w10 * xc[i10] + w11 * xc[i11];
      const float* wc = wk + c * C;           // 16 contiguous floats, uniform
#pragma unroll
      for (int o = 0; o < 16; ++o)
        acc[o] = fmaf(wc[o], s, acc[o]);
    }
  }

#pragma unroll
  for (int o = 0; o < 16; ++o)
    out[((size_t)(b * C + o0 + o)) * HW + p] = acc[o] + bd[o0 + o];
}

extern "C" void kernel_launch(void* const* d_in, const int* in_sizes, int n_in,
                              void* d_out, int out_size, void* d_ws, size_t ws_size,
                              hipStream_t stream) {
  const float* x    = (const float*)d_in[0];
  const float* c    = (const float*)d_in[1];
  const float* woff = (const float*)d_in[2];
  const float* boff = (const float*)d_in[3];
  const float* wdcn = (const float*)d_in[4];
  const float* bdcn = (const float*)d_in[5];
  float* out = (float*)d_out;

  float* wsf = (float*)d_ws;
  float* off_out = wsf;                       // 4*27*128*128 = 1,769,472 floats
  float* wt  = wsf + (size_t)BB * 27 * HW;    // 36,864 floats
  float* wot = wt + C * C * K;                // 15,552 floats

  prep_kernel<<<(C * C * K + 255) / 256, 256, 0, stream>>>(wdcn, woff, wt, wot);

  int npix = BB * H * W;                      // 65536
  dim3 goff(npix / 256, 3);
  conv_off_kernel<<<goff, 256, 0, stream>>>(c, wot, boff, off_out);
  dim3 gmain(npix / 256, 4);
  dcn_main_kernel<<<gmain, 256, 0, stream>>>(x, off_out, wt, bdcn, out);
}

// Round 3
// 172.761 us; speedup vs baseline: 2.4336x; 2.2988x over previous
//
#include <hip/hip_runtime.h>
#include <math.h>

#define BB 4
#define C 64
#define H 128
#define W 128
#define K 9
#define HW (H*W)
#define KC 576           // GEMM K dim: kc = k*64 + c
#define PIX 32           // pixels per block
#define ROWB 1168        // LDS row bytes: 576*2 + 16 pad

typedef __attribute__((ext_vector_type(8))) short s16x8;
typedef __attribute__((ext_vector_type(4))) float f32x4;

static __device__ __forceinline__ unsigned short f2bf(float f) {
  union { float f; unsigned u; } v; v.f = f;
  unsigned r = v.u + 0x7fffu + ((v.u >> 16) & 1u);   // RNE
  return (unsigned short)(r >> 16);
}

// ---------------- prep:
// wot [64][9][27] fp32  <- w_off [27][64][3][3]   (conv_off weights)
// wtb [64][576]  bf16   <- w_dcn [64][64][3][3], kc = k*64 + c
__global__ __launch_bounds__(256) void prep_kernel(
    const float* __restrict__ wd, const float* __restrict__ woff,
    float* __restrict__ wot, unsigned short* __restrict__ wtb) {
  int i = blockIdx.x * 256 + threadIdx.x;
  if (i < 27 * C * K) {         // 15552
    int t = i % K;
    int c = (i / K) % C;
    int o = i / (K * C);
    wot[(c * K + t) * 27 + o] = woff[i];
  }
  if (i < C * KC) {             // 36864
    int o = i / KC;
    int r = i % KC;
    int k = r >> 6;
    int c = r & 63;
    wtb[i] = f2bf(wd[(o * C + c) * 9 + k]);
  }
}

// ---------------- conv_offset: off_out[b][27][h][w] = conv3x3(c_in) + b_off
// grid: (npix/256, 3)  — blockIdx.y picks a 9-wide output-channel chunk
__global__ __launch_bounds__(256) void conv_off_kernel(
    const float* __restrict__ cin, const float* __restrict__ wot,
    const float* __restrict__ boff, float* __restrict__ off_out) {
  int tid = blockIdx.x * 256 + threadIdx.x;   // over B*H*W
  int o0 = blockIdx.y * 9;
  int w = tid & (W - 1);
  int h = (tid >> 7) & (H - 1);
  int b = tid >> 14;
  const float* cb = cin + (size_t)b * C * HW;

  float acc[9];
#pragma unroll
  for (int o = 0; o < 9; ++o) acc[o] = boff[o0 + o];

#pragma unroll 2
  for (int c = 0; c < C; ++c) {
    const float* cc = cb + c * HW;
    float v[9];
#pragma unroll
    for (int t = 0; t < 9; ++t) {
      int yy = h + t / 3 - 1;
      int xx = w + t % 3 - 1;
      bool ok = (yy >= 0) && (yy < H) && (xx >= 0) && (xx < W);
      v[t] = ok ? cc[yy * W + xx] : 0.0f;
    }
    const float* wc = wot + c * (9 * 27) + o0;  // uniform address -> s_loads
#pragma unroll
    for (int t = 0; t < 9; ++t)
#pragma unroll
      for (int o = 0; o < 9; ++o)
        acc[o] = fmaf(wc[t * 27 + o], v[t], acc[o]);
  }

  int p = h * W + w;
#pragma unroll
  for (int o = 0; o < 9; ++o)
    off_out[((size_t)b * 27 + o0 + o) * HW + p] = acc[o];
}

// ---------------- main: fused sample->LDS(bf16) -> MFMA GEMM
// block: 256 threads (4 waves), tile = 32 pixels (one half... quarter row)
// out[64o][pix] = W[64][576] @ samp[576][pix]
__global__ __launch_bounds__(256) void dcn_main_kernel(
    const float* __restrict__ x, const float* __restrict__ off,
    const unsigned short* __restrict__ wtb, const float* __restrict__ bd,
    float* __restrict__ out) {
  __shared__ __align__(16) unsigned char smem[PIX * ROWB];  // 37376 B

  int tid = threadIdx.x;
  int bid = blockIdx.x;

  // ---- stage 1: bilinear sampling (each thread: 1 pixel x 8 channels x 9 taps)
  int p  = tid & (PIX - 1);     // pixel within tile
  int cg = tid >> 5;            // channel group 0..7 (8 channels each)
  int pix = bid * PIX + p;
  int w = pix & (W - 1);
  int h = (pix >> 7) & (H - 1);
  int b = pix >> 14;
  int pp = pix & (HW - 1);

  const float* xb = x + (size_t)b * C * HW;
  const float* ob = off + (size_t)b * 27 * HW;

#pragma unroll 1
  for (int k = 0; k < K; ++k) {
    float dy = ob[(2 * k) * HW + pp];
    float dx = ob[(2 * k + 1) * HW + pp];
    float mv = ob[(18 + k) * HW + pp];
    float m = 1.0f / (1.0f + __expf(-mv));

    float py = (float)(h + k / 3 - 1) + dy;
    float px = (float)(w + k % 3 - 1) + dx;
    float y0f = floorf(py), x0f = floorf(px);
    int y0 = (int)y0f, x0 = (int)x0f;
    float wy1 = py - y0f, wx1 = px - x0f;
    float wy0 = 1.0f - wy1, wx0 = 1.0f - wx1;

    bool y0v = (y0 >= 0) && (y0 < H);
    bool y1v = (y0 + 1 >= 0) && (y0 + 1 < H);
    bool x0v = (x0 >= 0) && (x0 < W);
    bool x1v = (x0 + 1 >= 0) && (x0 + 1 < W);
    int y0c = min(max(y0, 0), H - 1), y1c = min(max(y0 + 1, 0), H - 1);
    int x0c = min(max(x0, 0), W - 1), x1c = min(max(x0 + 1, 0), W - 1);

    float w00 = wy0 * wx0 * (float)(y0v && x0v) * m;
    float w01 = wy0 * wx1 * (float)(y0v && x1v) * m;
    float w10 = wy1 * wx0 * (float)(y1v && x0v) * m;
    float w11 = wy1 * wx1 * (float)(y1v && x1v) * m;

    int i00 = y0c * W + x0c, i01 = y0c * W + x1c;
    int i10 = y1c * W + x0c, i11 = y1c * W + x1c;

    s16x8 u;
#pragma unroll
    for (int j = 0; j < 8; ++j) {
      const float* xc = xb + (cg * 8 + j) * HW;
      float s = w00 * xc[i00] + w01 * xc[i01] + w10 * xc[i10] + w11 * xc[i11];
      u[j] = (short)f2bf(s);
    }
    int colB = (k * 64 + cg * 8) * 2;          // 16B-aligned slot
    colB ^= ((p >> 3) & 7) << 4;               // XOR-swizzle slot bits
    *(s16x8*)(smem + p * ROWB + colB) = u;
  }

  __syncthreads();

  // ---- stage 2: MFMA GEMM  64o x 576 x 32pix
  int lane = tid & 63;
  int wid  = tid >> 6;          // o-tile
  int lr = lane & 15, lh = lane >> 4;

  const unsigned short* wrow = wtb + (wid * 16 + lr) * KC + lh * 8;

  f32x4 acc0 = {0.f, 0.f, 0.f, 0.f};
  f32x4 acc1 = {0.f, 0.f, 0.f, 0.f};

#pragma unroll 1
  for (int kb = 0; kb < KC / 32; ++kb) {       // 18 steps
    s16x8 a = *(const s16x8*)(wrow + kb * 32);
    int n0 = lr;                                // pixel rows 0..15
    int c0 = (kb * 64 + lh * 16) ^ (((n0 >> 3) & 7) << 4);
    s16x8 b0 = *(const s16x8*)(smem + n0 * ROWB + c0);
    acc0 = __builtin_amdgcn_mfma_f32_16x16x32_bf16(a, b0, acc0, 0, 0, 0);
    int n1 = 16 + lr;                           // pixel rows 16..31
    int c1 = (kb * 64 + lh * 16) ^ (((n1 >> 3) & 7) << 4);
    s16x8 b1 = *(const s16x8*)(smem + n1 * ROWB + c1);
    acc1 = __builtin_amdgcn_mfma_f32_16x16x32_bf16(a, b1, acc1, 0, 0, 0);
  }

  // ---- epilogue: C/D layout col=lane&15 (pixel), row=(lane>>4)*4+r (o)
  int pp0 = (bid * PIX) & (HW - 1);
#pragma unroll
  for (int r = 0; r < 4; ++r) {
    int o = wid * 16 + lh * 4 + r;
    float bias = bd[o];
    size_t base = ((size_t)(b * C + o)) * HW + pp0 + lr;
    out[base]      = acc0[r] + bias;
    out[base + 16] = acc1[r] + bias;
  }
}

extern "C" void kernel_launch(void* const* d_in, const int* in_sizes, int n_in,
                              void* d_out, int out_size, void* d_ws, size_t ws_size,
                              hipStream_t stream) {
  const float* x    = (const float*)d_in[0];
  const float* c    = (const float*)d_in[1];
  const float* woff = (const float*)d_in[2];
  const float* boff = (const float*)d_in[3];
  const float* wdcn = (const float*)d_in[4];
  const float* bdcn = (const float*)d_in[5];
  float* out = (float*)d_out;

  float* wsf = (float*)d_ws;
  float* off_out = wsf;                            // 1,769,472 floats
  float* wot = wsf + (size_t)BB * 27 * HW;         // 15,552 floats
  unsigned short* wtb = (unsigned short*)(wot + 27 * C * K);  // 36,864 bf16

  prep_kernel<<<(C * KC + 255) / 256, 256, 0, stream>>>(wdcn, woff, wot, wtb);

  int npix = BB * H * W;                           // 65536
  dim3 goff(npix / 256, 3);
  conv_off_kernel<<<goff, 256, 0, stream>>>(c, wot, boff, off_out);

  dcn_main_kernel<<<npix / PIX, 256, 0, stream>>>(x, off_out, wtb, bdcn, out);
}

// Round 4
// 102.716 us; speedup vs baseline: 4.0932x; 1.6819x over previous
//
#include <hip/hip_runtime.h>
#include <math.h>

#define BB 4
#define C 64
#define H 128
#define W 128
#define K 9
#define HW (H*W)
#define KC 576           // GEMM K dim: kc = k*64 + c
#define PIX 32           // pixels per block
#define ROWB 1168        // LDS row bytes: 576*2 + 16 pad

typedef __attribute__((ext_vector_type(8))) short s16x8;
typedef __attribute__((ext_vector_type(4))) float f32x4;

static __device__ __forceinline__ unsigned short f2bf(float f) {
  union { float f; unsigned u; } v; v.f = f;
  unsigned r = v.u + 0x7fffu + ((v.u >> 16) & 1u);   // RNE
  return (unsigned short)(r >> 16);
}
static __device__ __forceinline__ float bf2f(short s) {
  union { unsigned u; float f; } v;
  v.u = ((unsigned)(unsigned short)s) << 16;
  return v.f;
}

// ---------------- prep:
// wtb  [64][576] bf16 <- w_dcn [64][64][3][3], col = k*64 + c
// wotb [32][576] bf16 <- w_off [27][64][3][3], col = t*64 + c, rows 27..31 = 0
__global__ __launch_bounds__(256) void prep_kernel(
    const float* __restrict__ wd, const float* __restrict__ woff,
    unsigned short* __restrict__ wtb, unsigned short* __restrict__ wotb) {
  int i = blockIdx.x * 256 + threadIdx.x;
  if (i < C * KC) {             // 36864
    int o = i / KC;
    int r = i % KC;
    int k = r >> 6;
    int c = r & 63;
    wtb[i] = f2bf(wd[(o * C + c) * 9 + k]);
  }
  if (i < 32 * KC) {            // 18432
    int o = i / KC;
    int r = i % KC;
    int t = r >> 6;
    int c = r & 63;
    wotb[i] = (o < 27) ? f2bf(woff[(o * C + c) * 9 + t]) : (unsigned short)0;
  }
}

// ---------------- transpose x: [B][64][HW] fp32 -> xt [B*HW][64] bf16
// grid: 2048 blocks, 32 pixels each
__global__ __launch_bounds__(256) void xpose_kernel(
    const float* __restrict__ x, unsigned short* __restrict__ xt) {
  __shared__ unsigned short lds16[32 * 72];   // 4608 B, swizzled slots
  int t = threadIdx.x;
  int P0 = blockIdx.x * 32;
  int b = P0 >> 14;
  int pp0 = P0 & (HW - 1);

  int p = t & 31;
  int cg = t >> 5;              // 0..7
  const float* xb = x + (size_t)b * C * HW + pp0 + p;
  s16x8 u;
#pragma unroll
  for (int j = 0; j < 8; ++j)
    u[j] = (short)f2bf(xb[(cg * 8 + j) * HW]);
  *(s16x8*)(lds16 + p * 72 + ((cg ^ (p & 7)) << 3)) = u;

  __syncthreads();

  int q = t >> 3;               // pixel 0..31
  int s = t & 7;                // slot 0..7
  s16x8 v = *(const s16x8*)(lds16 + q * 72 + ((s ^ (q & 7)) << 3));
  *(s16x8*)(xt + (size_t)(P0 + q) * 64 + s * 8) = v;
}

// ---------------- conv_offset: fused im2col->LDS(bf16) -> MFMA GEMM
// out: off_out[b][27][h][w]; block = 32 pixels, 4 waves
__global__ __launch_bounds__(256, 4) void conv_off_kernel(
    const float* __restrict__ cin, const unsigned short* __restrict__ wotb,
    const float* __restrict__ boff, float* __restrict__ off_out) {
  __shared__ __align__(16) unsigned char smem[PIX * ROWB];  // 37376 B
  int tid = threadIdx.x;
  int P0 = blockIdx.x * PIX;
  int p = tid & 31;
  int cg = tid >> 5;
  int pix = P0 + p;
  int w = pix & (W - 1);
  int h = (pix >> 7) & (H - 1);
  int b = pix >> 14;
  const float* cb = cin + (size_t)b * C * HW;

#pragma unroll 3
  for (int t9 = 0; t9 < 9; ++t9) {
    int yy = h + t9 / 3 - 1;
    int xx = w + t9 % 3 - 1;
    bool ok = (yy >= 0) && (yy < H) && (xx >= 0) && (xx < W);
    int idx = yy * W + xx;
    s16x8 u;
#pragma unroll
    for (int j = 0; j < 8; ++j) {
      float v = ok ? cb[(cg * 8 + j) * HW + idx] : 0.0f;
      u[j] = (short)f2bf(v);
    }
    int colB = ((t9 * 64 + cg * 8) * 2) ^ (((p >> 3) & 7) << 4);
    *(s16x8*)(smem + p * ROWB + colB) = u;
  }

  __syncthreads();

  int lane = tid & 63;
  int wv = tid >> 6;            // 4 waves: otile = wv&1, pixel-half = wv>>1
  int otile = wv & 1;
  int nh = wv >> 1;
  int lr = lane & 15, lh = lane >> 4;

  const unsigned short* arow = wotb + (otile * 16 + lr) * KC + lh * 8;
  f32x4 acc = {0.f, 0.f, 0.f, 0.f};
  int n = nh * 16 + lr;
  int swzn = ((n >> 3) & 7) << 4;

#pragma unroll 1
  for (int kb = 0; kb < KC / 32; ++kb) {
    s16x8 a = *(const s16x8*)(arow + kb * 32);
    int cB = (kb * 64 + lh * 16) ^ swzn;
    s16x8 bf = *(const s16x8*)(smem + n * ROWB + cB);
    acc = __builtin_amdgcn_mfma_f32_16x16x32_bf16(a, bf, acc, 0, 0, 0);
  }

  int ppix = (P0 & (HW - 1)) + nh * 16 + lr;
#pragma unroll
  for (int r = 0; r < 4; ++r) {
    int o = otile * 16 + lh * 4 + r;
    if (o < 27)
      off_out[((size_t)b * 27 + o) * HW + ppix] = acc[r] + boff[o];
  }
}

// ---------------- main: bilinear sample (from NHWC bf16) ->LDS -> MFMA GEMM
__global__ __launch_bounds__(256, 4) void dcn_main_kernel(
    const unsigned short* __restrict__ xt, const float* __restrict__ off,
    const unsigned short* __restrict__ wtb, const float* __restrict__ bd,
    float* __restrict__ out) {
  __shared__ __align__(16) unsigned char smem[PIX * ROWB];  // 37376 B

  int tid = threadIdx.x;
  int bid = blockIdx.x;

  int p  = tid & (PIX - 1);
  int cg = tid >> 5;
  int pix = bid * PIX + p;
  int w = pix & (W - 1);
  int h = (pix >> 7) & (H - 1);
  int b = pix >> 14;
  int pp = pix & (HW - 1);

  const unsigned short* xtb = xt + (size_t)b * HW * 64;
  const float* ob = off + (size_t)b * 27 * HW;

#pragma unroll 1
  for (int k = 0; k < K; ++k) {
    float dy = ob[(2 * k) * HW + pp];
    float dx = ob[(2 * k + 1) * HW + pp];
    float mv = ob[(18 + k) * HW + pp];
    float m = 1.0f / (1.0f + __expf(-mv));

    float py = (float)(h + k / 3 - 1) + dy;
    float px = (float)(w + k % 3 - 1) + dx;
    float y0f = floorf(py), x0f = floorf(px);
    int y0 = (int)y0f, x0 = (int)x0f;
    float wy1 = py - y0f, wx1 = px - x0f;
    float wy0 = 1.0f - wy1, wx0 = 1.0f - wx1;

    bool y0v = (y0 >= 0) && (y0 < H);
    bool y1v = (y0 + 1 >= 0) && (y0 + 1 < H);
    bool x0v = (x0 >= 0) && (x0 < W);
    bool x1v = (x0 + 1 >= 0) && (x0 + 1 < W);
    int y0c = min(max(y0, 0), H - 1), y1c = min(max(y0 + 1, 0), H - 1);
    int x0c = min(max(x0, 0), W - 1), x1c = min(max(x0 + 1, 0), W - 1);

    float w00 = wy0 * wx0 * (float)(y0v && x0v) * m;
    float w01 = wy0 * wx1 * (float)(y0v && x1v) * m;
    float w10 = wy1 * wx0 * (float)(y1v && x0v) * m;
    float w11 = wy1 * wx1 * (float)(y1v && x1v) * m;

    // NHWC bf16 corner loads: 8 contiguous channels = 16 B each
    const unsigned short* c00p = xtb + (size_t)(y0c * W + x0c) * 64 + cg * 8;
    const unsigned short* c01p = xtb + (size_t)(y0c * W + x1c) * 64 + cg * 8;
    const unsigned short* c10p = xtb + (size_t)(y1c * W + x0c) * 64 + cg * 8;
    const unsigned short* c11p = xtb + (size_t)(y1c * W + x1c) * 64 + cg * 8;
    s16x8 c00 = *(const s16x8*)c00p;
    s16x8 c01 = *(const s16x8*)c01p;
    s16x8 c10 = *(const s16x8*)c10p;
    s16x8 c11 = *(const s16x8*)c11p;

    s16x8 u;
#pragma unroll
    for (int j = 0; j < 8; ++j) {
      float s = w00 * bf2f(c00[j]) + w01 * bf2f(c01[j])
              + w10 * bf2f(c10[j]) + w11 * bf2f(c11[j]);
      u[j] = (short)f2bf(s);
    }
    int colB = ((k * 64 + cg * 8) * 2) ^ (((p >> 3) & 7) << 4);
    *(s16x8*)(smem + p * ROWB + colB) = u;
  }

  __syncthreads();

  // ---- MFMA GEMM: 64o x 576 x 32pix
  int lane = tid & 63;
  int wid  = tid >> 6;          // o-tile 0..3
  int lr = lane & 15, lh = lane >> 4;

  const unsigned short* wrow = wtb + (wid * 16 + lr) * KC + lh * 8;

  f32x4 acc0 = {0.f, 0.f, 0.f, 0.f};
  f32x4 acc1 = {0.f, 0.f, 0.f, 0.f};
  int n0 = lr, n1 = 16 + lr;
  int swz0 = ((n0 >> 3) & 7) << 4;
  int swz1 = ((n1 >> 3) & 7) << 4;

#pragma unroll 1
  for (int kb = 0; kb < KC / 32; ++kb) {       // 18 steps
    s16x8 a = *(const s16x8*)(wrow + kb * 32);
    int c0 = (kb * 64 + lh * 16) ^ swz0;
    s16x8 b0 = *(const s16x8*)(smem + n0 * ROWB + c0);
    acc0 = __builtin_amdgcn_mfma_f32_16x16x32_bf16(a, b0, acc0, 0, 0, 0);
    int c1 = (kb * 64 + lh * 16) ^ swz1;
    s16x8 b1 = *(const s16x8*)(smem + n1 * ROWB + c1);
    acc1 = __builtin_amdgcn_mfma_f32_16x16x32_bf16(a, b1, acc1, 0, 0, 0);
  }

  // ---- epilogue: C/D layout col=lane&15 (pixel), row=(lane>>4)*4+r (o)
  int pp0 = (bid * PIX) & (HW - 1);
#pragma unroll
  for (int r = 0; r < 4; ++r) {
    int o = wid * 16 + lh * 4 + r;
    float bias = bd[o];
    size_t base = ((size_t)(b * C + o)) * HW + pp0 + lr;
    out[base]      = acc0[r] + bias;
    out[base + 16] = acc1[r] + bias;
  }
}

extern "C" void kernel_launch(void* const* d_in, const int* in_sizes, int n_in,
                              void* d_out, int out_size, void* d_ws, size_t ws_size,
                              hipStream_t stream) {
  const float* x    = (const float*)d_in[0];
  const float* c    = (const float*)d_in[1];
  const float* woff = (const float*)d_in[2];
  const float* boff = (const float*)d_in[3];
  const float* wdcn = (const float*)d_in[4];
  const float* bdcn = (const float*)d_in[5];
  float* out = (float*)d_out;

  float* wsf = (float*)d_ws;
  float* off_out = wsf;                                  // 1,769,472 f
  unsigned short* xt   = (unsigned short*)(wsf + 1769472);  // 4,194,304 bf16
  unsigned short* wtb  = xt + 4194304;                   // 36,864 bf16
  unsigned short* wotb = wtb + 36864;                    // 18,432 bf16

  prep_kernel<<<(C * KC + 255) / 256, 256, 0, stream>>>(wdcn, woff, wtb, wotb);

  int npix = BB * H * W;                                 // 65536
  xpose_kernel<<<npix / 32, 256, 0, stream>>>(x, xt);
  conv_off_kernel<<<npix / PIX, 256, 0, stream>>>(c, wotb, boff, off_out);
  dcn_main_kernel<<<npix / PIX, 256, 0, stream>>>(xt, off_out, wtb, bdcn, out);
}

// Round 5
// 73.652 us; speedup vs baseline: 5.7085x; 1.3946x over previous
//
#include <hip/hip_runtime.h>
#include <math.h>

#define BB 4
#define C 64
#define H 128
#define W 128
#define K 9
#define HW (H*W)
#define KC 576           // GEMM K dim: col = k*64 + c
#define PIX 32           // pixels per block
#define ROWB 1168        // LDS row bytes: 576*2 + 16 pad

typedef __attribute__((ext_vector_type(4))) float f32x4;
typedef __attribute__((ext_vector_type(8))) _Float16 f16x8;

static __device__ __forceinline__ f16x8 splat8(float f) {
  _Float16 h = (_Float16)f;
  f16x8 v = {h, h, h, h, h, h, h, h};
  return v;
}

// ---------------- prep:
// wtb  [64][576] f16 <- w_dcn [64][64][3][3], col = k*64 + c
// wotb [32][576] f16 <- w_off [27][64][3][3], col = t*64 + c, rows 27..31 = 0
__global__ __launch_bounds__(256) void prep_kernel(
    const float* __restrict__ wd, const float* __restrict__ woff,
    _Float16* __restrict__ wtb, _Float16* __restrict__ wotb) {
  int i = blockIdx.x * 256 + threadIdx.x;
  if (i < C * KC) {             // 36864
    int o = i / KC;
    int r = i % KC;
    int k = r >> 6;
    int c = r & 63;
    wtb[i] = (_Float16)wd[(o * C + c) * 9 + k];
  }
  if (i < 32 * KC) {            // 18432
    int o = i / KC;
    int r = i % KC;
    int t = r >> 6;
    int c = r & 63;
    wotb[i] = (o < 27) ? (_Float16)woff[(o * C + c) * 9 + t] : (_Float16)0.f;
  }
}

// ---------------- transpose: [B][64][HW] fp32 -> [B*HW][64] f16
// grid: (2048, 2)  y=0: x->xt, y=1: c->ct
__global__ __launch_bounds__(256) void xpose_kernel(
    const float* __restrict__ x, const float* __restrict__ cin,
    _Float16* __restrict__ xt, _Float16* __restrict__ ct) {
  __shared__ _Float16 lds16[32 * 72];
  const float* src = blockIdx.y ? cin : x;
  _Float16* dst = blockIdx.y ? ct : xt;

  int t = threadIdx.x;
  int P0 = blockIdx.x * 32;
  int b = P0 >> 14;
  int pp0 = P0 & (HW - 1);

  int p = t & 31;
  int cg = t >> 5;              // 0..7
  const float* xb = src + (size_t)b * C * HW + pp0 + p;
  f16x8 u;
#pragma unroll
  for (int j = 0; j < 8; ++j)
    u[j] = (_Float16)xb[(cg * 8 + j) * HW];
  *(f16x8*)(lds16 + p * 72 + ((cg ^ (p & 7)) << 3)) = u;

  __syncthreads();

  int q = t >> 3;               // pixel 0..31
  int s = t & 7;                // slot 0..7
  f16x8 v = *(const f16x8*)(lds16 + q * 72 + ((s ^ (q & 7)) << 3));
  *(f16x8*)(dst + (size_t)(P0 + q) * 64 + s * 8) = v;
}

// ---------------- conv_offset: NHWC f16 im2col->LDS -> MFMA GEMM
__global__ __launch_bounds__(256, 4) void conv_off_kernel(
    const _Float16* __restrict__ ct, const _Float16* __restrict__ wotb,
    const float* __restrict__ boff, float* __restrict__ off_out) {
  __shared__ __align__(16) unsigned char smem[PIX * ROWB];  // 37376 B
  int tid = threadIdx.x;
  int P0 = blockIdx.x * PIX;
  int p  = tid >> 3;            // pixel 0..31
  int cg = tid & 7;             // channel group 0..7
  int pix = P0 + p;
  int w = pix & (W - 1);
  int h = (pix >> 7) & (H - 1);
  int b = pix >> 14;
  const _Float16* cb = ct + (size_t)b * HW * 64 + cg * 8;

#pragma unroll
  for (int t9 = 0; t9 < 9; ++t9) {
    int yy = h + t9 / 3 - 1;
    int xx = w + t9 % 3 - 1;
    bool ok = (yy >= 0) && (yy < H) && (xx >= 0) && (xx < W);
    f16x8 v = {};
    if (ok) v = *(const f16x8*)(cb + (size_t)(yy * W + xx) * 64);
    int colB = ((t9 * 64 + cg * 8) * 2) ^ (((p >> 3) & 7) << 4);
    *(f16x8*)(smem + p * ROWB + colB) = v;
  }

  __syncthreads();

  int lane = tid & 63;
  int wv = tid >> 6;            // otile = wv&1, pixel-half = wv>>1
  int otile = wv & 1;
  int nh = wv >> 1;
  int lr = lane & 15, lh = lane >> 4;

  const _Float16* arow = wotb + (otile * 16 + lr) * KC + lh * 8;
  f32x4 acc = {0.f, 0.f, 0.f, 0.f};
  int n = nh * 16 + lr;
  int swzn = ((n >> 3) & 7) << 4;

#pragma unroll 1
  for (int kb = 0; kb < KC / 32; ++kb) {
    f16x8 a = *(const f16x8*)(arow + kb * 32);
    int cB = (kb * 64 + lh * 16) ^ swzn;
    f16x8 bf = *(const f16x8*)(smem + n * ROWB + cB);
    acc = __builtin_amdgcn_mfma_f32_16x16x32_f16(a, bf, acc, 0, 0, 0);
  }

  int ppix = (P0 & (HW - 1)) + nh * 16 + lr;
#pragma unroll
  for (int r = 0; r < 4; ++r) {
    int o = otile * 16 + lh * 4 + r;
    if (o < 27)
      off_out[((size_t)b * 27 + o) * HW + ppix] = acc[r] + boff[o];
  }
}

// ---------------- main: bilinear sample (NHWC f16, packed interp) -> MFMA
__global__ __launch_bounds__(256, 4) void dcn_main_kernel(
    const _Float16* __restrict__ xt, const float* __restrict__ off,
    const _Float16* __restrict__ wtb, const float* __restrict__ bd,
    float* __restrict__ out) {
  __shared__ __align__(16) unsigned char smem[PIX * ROWB];  // 37376 B

  int tid = threadIdx.x;
  int bid = blockIdx.x;

  int p  = tid >> 3;            // pixel 0..31   (8 lanes per pixel)
  int cg = tid & 7;             // channel group 0..7
  int pix = bid * PIX + p;
  int w = pix & (W - 1);
  int h = (pix >> 7) & (H - 1);
  int b = pix >> 14;
  int pp = pix & (HW - 1);

  const _Float16* xtb = xt + (size_t)b * HW * 64 + cg * 8;
  const float* ob = off + (size_t)b * 27 * HW + pp;

#pragma unroll 3
  for (int k = 0; k < K; ++k) {
    float dy = ob[(2 * k) * HW];
    float dx = ob[(2 * k + 1) * HW];
    float mv = ob[(18 + k) * HW];
    float m = 1.0f / (1.0f + __expf(-mv));

    float py = (float)(h + k / 3 - 1) + dy;
    float px = (float)(w + k % 3 - 1) + dx;
    float y0f = floorf(py), x0f = floorf(px);
    int y0 = (int)y0f, x0 = (int)x0f;
    float wy1 = py - y0f, wx1 = px - x0f;
    float wy0 = 1.0f - wy1, wx0 = 1.0f - wx1;

    bool y0v = (y0 >= 0) && (y0 < H);
    bool y1v = (y0 + 1 >= 0) && (y0 + 1 < H);
    bool x0v = (x0 >= 0) && (x0 < W);
    bool x1v = (x0 + 1 >= 0) && (x0 + 1 < W);
    int y0c = min(max(y0, 0), H - 1), y1c = min(max(y0 + 1, 0), H - 1);
    int x0c = min(max(x0, 0), W - 1), x1c = min(max(x0 + 1, 0), W - 1);

    float w00 = wy0 * wx0 * (float)(y0v && x0v) * m;
    float w01 = wy0 * wx1 * (float)(y0v && x1v) * m;
    float w10 = wy1 * wx0 * (float)(y1v && x0v) * m;
    float w11 = wy1 * wx1 * (float)(y1v && x1v) * m;

    // NHWC f16 corner loads: one whole 128B line per pixel per corner
    f16x8 c00 = *(const f16x8*)(xtb + (size_t)(y0c * W + x0c) * 64);
    f16x8 c01 = *(const f16x8*)(xtb + (size_t)(y0c * W + x1c) * 64);
    f16x8 c10 = *(const f16x8*)(xtb + (size_t)(y1c * W + x0c) * 64);
    f16x8 c11 = *(const f16x8*)(xtb + (size_t)(y1c * W + x1c) * 64);

    // packed fp16 bilinear (v_pk_fma_f16)
    f16x8 s = c00 * splat8(w00);
    s += c01 * splat8(w01);
    s += c10 * splat8(w10);
    s += c11 * splat8(w11);

    int colB = ((k * 64 + cg * 8) * 2) ^ (((p >> 3) & 7) << 4);
    *(f16x8*)(smem + p * ROWB + colB) = s;
  }

  __syncthreads();

  // ---- MFMA GEMM: 64o x 576 x 32pix
  int lane = tid & 63;
  int wid  = tid >> 6;          // o-tile 0..3
  int lr = lane & 15, lh = lane >> 4;

  const _Float16* wrow = wtb + (wid * 16 + lr) * KC + lh * 8;

  f32x4 acc0 = {0.f, 0.f, 0.f, 0.f};
  f32x4 acc1 = {0.f, 0.f, 0.f, 0.f};
  int n0 = lr, n1 = 16 + lr;
  int swz0 = ((n0 >> 3) & 7) << 4;
  int swz1 = ((n1 >> 3) & 7) << 4;

#pragma unroll 1
  for (int kb = 0; kb < KC / 32; ++kb) {       // 18 steps
    f16x8 a = *(const f16x8*)(wrow + kb * 32);
    int c0 = (kb * 64 + lh * 16) ^ swz0;
    f16x8 b0 = *(const f16x8*)(smem + n0 * ROWB + c0);
    acc0 = __builtin_amdgcn_mfma_f32_16x16x32_f16(a, b0, acc0, 0, 0, 0);
    int c1 = (kb * 64 + lh * 16) ^ swz1;
    f16x8 b1 = *(const f16x8*)(smem + n1 * ROWB + c1);
    acc1 = __builtin_amdgcn_mfma_f32_16x16x32_f16(a, b1, acc1, 0, 0, 0);
  }

  // ---- epilogue: C/D layout col=lane&15 (pixel), row=(lane>>4)*4+r (o)
  int pp0 = (bid * PIX) & (HW - 1);
#pragma unroll
  for (int r = 0; r < 4; ++r) {
    int o = wid * 16 + lh * 4 + r;
    float bias = bd[o];
    size_t base = ((size_t)(b * C + o)) * HW + pp0 + lr;
    out[base]      = acc0[r] + bias;
    out[base + 16] = acc1[r] + bias;
  }
}

extern "C" void kernel_launch(void* const* d_in, const int* in_sizes, int n_in,
                              void* d_out, int out_size, void* d_ws, size_t ws_size,
                              hipStream_t stream) {
  const float* x    = (const float*)d_in[0];
  const float* c    = (const float*)d_in[1];
  const float* woff = (const float*)d_in[2];
  const float* boff = (const float*)d_in[3];
  const float* wdcn = (const float*)d_in[4];
  const float* bdcn = (const float*)d_in[5];
  float* out = (float*)d_out;

  float* wsf = (float*)d_ws;
  float* off_out = wsf;                               // 1,769,472 f32
  _Float16* xt   = (_Float16*)(wsf + 1769472);        // 4,194,304 f16
  _Float16* ct   = xt + 4194304;                      // 4,194,304 f16
  _Float16* wtb  = ct + 4194304;                      // 36,864 f16
  _Float16* wotb = wtb + 36864;                       // 18,432 f16

  prep_kernel<<<(C * KC + 255) / 256, 256, 0, stream>>>(wdcn, woff, wtb, wotb);

  int npix = BB * H * W;                              // 65536
  dim3 gx(npix / 32, 2);
  xpose_kernel<<<gx, 256, 0, stream>>>(x, c, xt, ct);
  conv_off_kernel<<<npix / PIX, 256, 0, stream>>>(ct, wotb, boff, off_out);
  dcn_main_kernel<<<npix / PIX, 256, 0, stream>>>(xt, off_out, wtb, bdcn, out);
}

// Round 6
// 62.341 us; speedup vs baseline: 6.7442x; 1.1814x over previous
//
#include <hip/hip_runtime.h>
#include <math.h>

#define BB 4
#define C 64
#define H 128
#define W 128
#define K 9
#define HW (H*W)
#define KC 576           // GEMM K dim: col = k*64 + c
#define PIX 32           // pixels per block
#define ROWB 1168        // LDS staging row bytes: 576*2 + 16 pad
#define OFFW 36          // offbuf row stride in f32 (mult of 4 -> b128 aligned)

typedef __attribute__((ext_vector_type(4))) float f32x4;
typedef __attribute__((ext_vector_type(8))) _Float16 f16x8;

static __device__ __forceinline__ f16x8 splat8(float f) {
  _Float16 h = (_Float16)f;
  f16x8 v = {h, h, h, h, h, h, h, h};
  return v;
}

// ---------------- kernel 1: transpose x,c to NHWC f16 + weight prep (folded)
// grid: (2048, 2)  y=0: x->xt ; y=1: c->ct (+ first 144 blocks do weight prep)
__global__ __launch_bounds__(256) void xpose_prep_kernel(
    const float* __restrict__ x, const float* __restrict__ cin,
    const float* __restrict__ wd, const float* __restrict__ woff,
    _Float16* __restrict__ xt, _Float16* __restrict__ ct,
    _Float16* __restrict__ wtb, _Float16* __restrict__ wotb) {
  __shared__ _Float16 lds16[32 * 72];
  int t = threadIdx.x;

  if (blockIdx.y == 1 && blockIdx.x < 144) {
    int i = blockIdx.x * 256 + t;
    if (i < C * KC) {           // wtb [64][576] <- w_dcn, col = k*64+c
      int o = i / KC, r = i % KC, k = r >> 6, c = r & 63;
      wtb[i] = (_Float16)wd[(o * C + c) * 9 + k];
    }
    if (i < 32 * KC) {          // wotb [32][576] <- w_off, rows 27..31 = 0
      int o = i / KC, r = i % KC, t9 = r >> 6, c = r & 63;
      wotb[i] = (o < 27) ? (_Float16)woff[(o * C + c) * 9 + t9] : (_Float16)0.f;
    }
  }

  const float* src = blockIdx.y ? cin : x;
  _Float16* dst = blockIdx.y ? ct : xt;

  int P0 = blockIdx.x * 32;
  int b = P0 >> 14;
  int pp0 = P0 & (HW - 1);

  int p = t & 31;
  int cg = t >> 5;              // 0..7
  const float* xb = src + (size_t)b * C * HW + pp0 + p;
  f16x8 u;
#pragma unroll
  for (int j = 0; j < 8; ++j)
    u[j] = (_Float16)xb[(cg * 8 + j) * HW];
  *(f16x8*)(lds16 + p * 72 + ((cg ^ (p & 7)) << 3)) = u;

  __syncthreads();

  int q = t >> 3;               // pixel 0..31
  int s = t & 7;                // slot 0..7
  f16x8 v = *(const f16x8*)(lds16 + q * 72 + ((s ^ (q & 7)) << 3));
  *(f16x8*)(dst + (size_t)(P0 + q) * 64 + s * 8) = v;
}

// ---------------- kernel 2: fused conv_offset + modulated deformable conv
// block = 32 pixels, 4 waves.
__global__ __launch_bounds__(256, 4) void dcn_fused_kernel(
    const _Float16* __restrict__ xt, const _Float16* __restrict__ ct,
    const _Float16* __restrict__ wtb, const _Float16* __restrict__ wotb,
    const float* __restrict__ boff, const float* __restrict__ bd,
    float* __restrict__ out) {
  __shared__ __align__(16) unsigned char smem[PIX * ROWB];  // 37376 B
  float* offbuf = (float*)smem;                             // [32][OFFW] reuse

  int tid = threadIdx.x;
  int bid = blockIdx.x;

  int p  = tid >> 3;            // pixel 0..31   (8 lanes per pixel)
  int cg = tid & 7;             // channel group 0..7
  int pix = bid * PIX + p;
  int w = pix & (W - 1);
  int h = (pix >> 7) & (H - 1);
  int b = pix >> 14;

  int lane = tid & 63;
  int wv = tid >> 6;
  int lr = lane & 15, lh = lane >> 4;

  // ======== stage A: c-tile im2col -> smem (f16) ========
  {
    const _Float16* cb = ct + (size_t)b * HW * 64 + cg * 8;
#pragma unroll
    for (int t9 = 0; t9 < 9; ++t9) {
      int yy = h + t9 / 3 - 1;
      int xx = w + t9 % 3 - 1;
      bool ok = (yy >= 0) && (yy < H) && (xx >= 0) && (xx < W);
      f16x8 v = {};
      if (ok) v = *(const f16x8*)(cb + (size_t)(yy * W + xx) * 64);
      int colB = ((t9 * 64 + cg * 8) * 2) ^ (((p >> 3) & 7) << 4);
      *(f16x8*)(smem + p * ROWB + colB) = v;
    }
  }
  __syncthreads();

  // ======== GEMM1: off[32o][32p] = wotb[32][576] @ ctile[576][32p] ========
  {
    int otile = wv & 1;
    int nh = wv >> 1;
    const _Float16* arow = wotb + (otile * 16 + lr) * KC + lh * 8;
    f32x4 acc = {0.f, 0.f, 0.f, 0.f};
    int n = nh * 16 + lr;
    int swzn = ((n >> 3) & 7) << 4;
#pragma unroll 1
    for (int kb = 0; kb < KC / 32; ++kb) {
      f16x8 a = *(const f16x8*)(arow + kb * 32);
      f16x8 bf = *(const f16x8*)(smem + n * ROWB + ((kb * 64 + lh * 16) ^ swzn));
      acc = __builtin_amdgcn_mfma_f32_16x16x32_f16(a, bf, acc, 0, 0, 0);
    }
    __syncthreads();            // staging reads done; safe to overwrite as offbuf

    // write offbuf[p][o] = acc + boff  (C/D: col=lr -> pixel, row -> o)
    int obase = otile * 16 + lh * 4;
    f32x4 v;
#pragma unroll
    for (int r = 0; r < 4; ++r) {
      int o = obase + r;
      v[r] = acc[r] + ((o < 27) ? boff[o] : 0.f);
    }
    *(f32x4*)(offbuf + n * OFFW + obase) = v;
  }
  __syncthreads();

  // ======== pull this pixel's 27 offset/mask values into registers ========
  f32x4 rv[7];
#pragma unroll
  for (int j = 0; j < 7; ++j)
    rv[j] = *(const f32x4*)(offbuf + p * OFFW + 4 * j);
  __syncthreads();              // all reads done; stage B may overwrite

#define OFFV(i) (rv[(i) >> 2][(i) & 3])

  // ======== stage B: bilinear sample x (NHWC f16, packed interp) ========
  {
    const _Float16* xtb = xt + (size_t)b * HW * 64 + cg * 8;
#pragma unroll
    for (int k = 0; k < K; ++k) {
      float dy = OFFV(2 * k);
      float dx = OFFV(2 * k + 1);
      float mv = OFFV(18 + k);
      float m = 1.0f / (1.0f + __expf(-mv));

      float py = (float)(h + k / 3 - 1) + dy;
      float px = (float)(w + k % 3 - 1) + dx;
      float y0f = floorf(py), x0f = floorf(px);
      int y0 = (int)y0f, x0 = (int)x0f;
      float wy1 = py - y0f, wx1 = px - x0f;
      float wy0 = 1.0f - wy1, wx0 = 1.0f - wx1;

      bool y0v = (y0 >= 0) && (y0 < H);
      bool y1v = (y0 + 1 >= 0) && (y0 + 1 < H);
      bool x0v = (x0 >= 0) && (x0 < W);
      bool x1v = (x0 + 1 >= 0) && (x0 + 1 < W);
      int y0c = min(max(y0, 0), H - 1), y1c = min(max(y0 + 1, 0), H - 1);
      int x0c = min(max(x0, 0), W - 1), x1c = min(max(x0 + 1, 0), W - 1);

      float w00 = wy0 * wx0 * (float)(y0v && x0v) * m;
      float w01 = wy0 * wx1 * (float)(y0v && x1v) * m;
      float w10 = wy1 * wx0 * (float)(y1v && x0v) * m;
      float w11 = wy1 * wx1 * (float)(y1v && x1v) * m;

      f16x8 c00 = *(const f16x8*)(xtb + (size_t)(y0c * W + x0c) * 64);
      f16x8 c01 = *(const f16x8*)(xtb + (size_t)(y0c * W + x1c) * 64);
      f16x8 c10 = *(const f16x8*)(xtb + (size_t)(y1c * W + x0c) * 64);
      f16x8 c11 = *(const f16x8*)(xtb + (size_t)(y1c * W + x1c) * 64);

      f16x8 s = c00 * splat8(w00);
      s += c01 * splat8(w01);
      s += c10 * splat8(w10);
      s += c11 * splat8(w11);

      int colB = ((k * 64 + cg * 8) * 2) ^ (((p >> 3) & 7) << 4);
      *(f16x8*)(smem + p * ROWB + colB) = s;
    }
  }
  __syncthreads();

  // ======== GEMM2: out[64o][32p] = wtb[64][576] @ samp[576][32p] ========
  {
    int wid = wv;               // o-tile 0..3
    const _Float16* wrow = wtb + (wid * 16 + lr) * KC + lh * 8;

    f32x4 acc0 = {0.f, 0.f, 0.f, 0.f};
    f32x4 acc1 = {0.f, 0.f, 0.f, 0.f};
    int n0 = lr, n1 = 16 + lr;
    int swz0 = ((n0 >> 3) & 7) << 4;
    int swz1 = ((n1 >> 3) & 7) << 4;

#pragma unroll 1
    for (int kb = 0; kb < KC / 32; ++kb) {     // 18 steps
      f16x8 a = *(const f16x8*)(wrow + kb * 32);
      f16x8 b0 = *(const f16x8*)(smem + n0 * ROWB + ((kb * 64 + lh * 16) ^ swz0));
      acc0 = __builtin_amdgcn_mfma_f32_16x16x32_f16(a, b0, acc0, 0, 0, 0);
      f16x8 b1 = *(const f16x8*)(smem + n1 * ROWB + ((kb * 64 + lh * 16) ^ swz1));
      acc1 = __builtin_amdgcn_mfma_f32_16x16x32_f16(a, b1, acc1, 0, 0, 0);
    }

    int pp0 = (bid * PIX) & (HW - 1);
#pragma unroll
    for (int r = 0; r < 4; ++r) {
      int o = wid * 16 + lh * 4 + r;
      float bias = bd[o];
      size_t base = ((size_t)(b * C + o)) * HW + pp0 + lr;
      out[base]      = acc0[r] + bias;
      out[base + 16] = acc1[r] + bias;
    }
  }
}

extern "C" void kernel_launch(void* const* d_in, const int* in_sizes, int n_in,
                              void* d_out, int out_size, void* d_ws, size_t ws_size,
                              hipStream_t stream) {
  const float* x    = (const float*)d_in[0];
  const float* c    = (const float*)d_in[1];
  const float* woff = (const float*)d_in[2];
  const float* boff = (const float*)d_in[3];
  const float* wdcn = (const float*)d_in[4];
  const float* bdcn = (const float*)d_in[5];
  float* out = (float*)d_out;

  _Float16* xt   = (_Float16*)d_ws;                   // 4,194,304 f16
  _Float16* ct   = xt + 4194304;                      // 4,194,304 f16
  _Float16* wtb  = ct + 4194304;                      // 36,864 f16
  _Float16* wotb = wtb + 36864;                       // 18,432 f16

  int npix = BB * H * W;                              // 65536
  dim3 gx(npix / 32, 2);
  xpose_prep_kernel<<<gx, 256, 0, stream>>>(x, c, wdcn, woff, xt, ct, wtb, wotb);
  dcn_fused_kernel<<<npix / PIX, 256, 0, stream>>>(xt, ct, wtb, wotb, boff, bdcn, out);
}